// Round 11
// baseline (67365.979 us; speedup 1.0000x reference)
//
#include <hip/hip_runtime.h>

#define SCOPE_AGENT __HIP_MEMORY_SCOPE_AGENT

// ws layout (float offsets)
// PACKED-4 exchange layout for hsG/hPg/sGg/uG: element (k,lane) at
// ((k>>2)*256 + lane*4 + (k&3)). 16B-group loads via global_load_dwordx4 sc1.
#define OFF_HS    0          // [2] packed [128][64][4] hidden states
#define OFF_HP    65536      // [2] packed h'
#define OFF_SG    131072     // [2] packed sorted
#define OFF_U     196608     // [2] packed [256][64][4] u
#define OFF_CTR   327680     // barrier: flag[256] lines (uint stride 32)
#define OFF_T1    393216     // [2][1024][1024] compose scratch
#define OFF_M     2490368    // [2][1024][1024] composed M
#define OFF_GIX   4587520    // [512][512][3][64] precomputed W_ih. x_t (layer 0)
#define OFF_XT    4587520    // fallback: packed [512][128][64][4] transposed x
#define WS_GIX    54919168   // floats incl gix (~220 MB)
#define WS_XT     21364736   // floats incl xT (~85 MB)

typedef float f32x4 __attribute__((ext_vector_type(4)));

__device__ __forceinline__ float sigm(float x) { return 1.f / (1.f + expf(-x)); }

__device__ __forceinline__ float ld_sc1(const float* p) {
    return __hip_atomic_load(p, __ATOMIC_RELAXED, SCOPE_AGENT);
}
__device__ __forceinline__ void st_sc1(float* p, float v) {
    __hip_atomic_store(p, v, __ATOMIC_RELAXED, SCOPE_AGENT);
}
__device__ __forceinline__ void st2(float* p, float a, float b) {
    unsigned long long v = ((unsigned long long)__float_as_uint(b) << 32) |
                           (unsigned long long)__float_as_uint(a);
    __hip_atomic_store((unsigned long long*)p, v, __ATOMIC_RELAXED, SCOPE_AGENT);
}

// 8 x 16B agent-scope loads (8 consecutive packed groups), one latency round.
__device__ __forceinline__ void ld4b8(const float* base, f32x4* v) {
    const float* b2 = base + 1024;
    asm volatile(
        "global_load_dwordx4 %0, %8, off sc1\n\t"
        "global_load_dwordx4 %1, %8, off offset:1024 sc1\n\t"
        "global_load_dwordx4 %2, %8, off offset:2048 sc1\n\t"
        "global_load_dwordx4 %3, %8, off offset:3072 sc1\n\t"
        "global_load_dwordx4 %4, %9, off sc1\n\t"
        "global_load_dwordx4 %5, %9, off offset:1024 sc1\n\t"
        "global_load_dwordx4 %6, %9, off offset:2048 sc1\n\t"
        "global_load_dwordx4 %7, %9, off offset:3072 sc1\n\t"
        "s_waitcnt vmcnt(0)"
        : "=&v"(v[0]), "=&v"(v[1]), "=&v"(v[2]), "=&v"(v[3]),
          "=&v"(v[4]), "=&v"(v[5]), "=&v"(v[6]), "=&v"(v[7])
        : "v"(base), "v"(b2)
        : "memory");
}

// 16 x 16B loads from two regions (8 groups each), SINGLE waitcnt -> one round.
__device__ __forceinline__ void ld4b8x2(const float* baseA, const float* baseB,
                                        f32x4* va, f32x4* vb) {
    const float* a2 = baseA + 1024;
    const float* b2 = baseB + 1024;
    asm volatile(
        "global_load_dwordx4 %0, %16, off sc1\n\t"
        "global_load_dwordx4 %1, %16, off offset:1024 sc1\n\t"
        "global_load_dwordx4 %2, %16, off offset:2048 sc1\n\t"
        "global_load_dwordx4 %3, %16, off offset:3072 sc1\n\t"
        "global_load_dwordx4 %4, %17, off sc1\n\t"
        "global_load_dwordx4 %5, %17, off offset:1024 sc1\n\t"
        "global_load_dwordx4 %6, %17, off offset:2048 sc1\n\t"
        "global_load_dwordx4 %7, %17, off offset:3072 sc1\n\t"
        "global_load_dwordx4 %8, %18, off sc1\n\t"
        "global_load_dwordx4 %9, %18, off offset:1024 sc1\n\t"
        "global_load_dwordx4 %10, %18, off offset:2048 sc1\n\t"
        "global_load_dwordx4 %11, %18, off offset:3072 sc1\n\t"
        "global_load_dwordx4 %12, %19, off sc1\n\t"
        "global_load_dwordx4 %13, %19, off offset:1024 sc1\n\t"
        "global_load_dwordx4 %14, %19, off offset:2048 sc1\n\t"
        "global_load_dwordx4 %15, %19, off offset:3072 sc1\n\t"
        "s_waitcnt vmcnt(0)"
        : "=&v"(va[0]), "=&v"(va[1]), "=&v"(va[2]), "=&v"(va[3]),
          "=&v"(va[4]), "=&v"(va[5]), "=&v"(va[6]), "=&v"(va[7]),
          "=&v"(vb[0]), "=&v"(vb[1]), "=&v"(vb[2]), "=&v"(vb[3]),
          "=&v"(vb[4]), "=&v"(vb[5]), "=&v"(vb[6]), "=&v"(vb[7])
        : "v"(baseA), "v"(a2), "v"(baseB), "v"(b2)
        : "memory");
}

// Flat single-hop barrier (R10). Generation-tagged, no atomics, no resets.
__device__ __forceinline__ void gbar(unsigned* flags, unsigned g) {
    __syncthreads();
    const int tid = threadIdx.x;
    if (tid == 0)
        __hip_atomic_store(&flags[blockIdx.x << 5], g, __ATOMIC_RELAXED, SCOPE_AGENT);
    if (tid < 256) {
        while (__hip_atomic_load(&flags[tid << 5], __ATOMIC_RELAXED, SCOPE_AGENT) < g)
            __builtin_amdgcn_s_sleep(1);
    }
    __syncthreads();
}

__global__ void k_init(const float* __restrict__ h0, float* __restrict__ ws) {
    int idx = blockIdx.x * blockDim.x + threadIdx.x;   // 65536
    int l = idx >> 15, k = (idx & 32767) >> 6, lane = idx & 63;
    ws[OFF_HS + (l << 15) + ((k >> 2) << 8) + (lane << 2) + (k & 3)] = h0[(l << 9) + k];
    if (idx < 8704) ((unsigned*)(ws + OFF_CTR))[idx] = 0u;
}

// gix[t][j][g][b] = sum_k wih0[g*512+j][k] * x[b][t*512+k]
__global__ void k_gix(const float* __restrict__ x, const float* __restrict__ wih,
                      float* __restrict__ gix) {
    __shared__ float xs[128][65];
    __shared__ float ww[32][129];
    int t = blockIdx.x, rb = blockIdx.y * 32;
    int tid = threadIdx.x;
    int rw = tid >> 6, b = tid & 63;
    float acc[8] = {0.f, 0.f, 0.f, 0.f, 0.f, 0.f, 0.f, 0.f};
    for (int kc = 0; kc < 4; kc++) {
        __syncthreads();
        for (int i = tid; i < 8192; i += 256) {
            int k = i & 127, b2 = i >> 7;
            xs[k][b2] = x[(size_t)b2 * 262144 + (size_t)t * 512 + kc * 128 + k];
        }
        for (int i = tid; i < 4096; i += 256) {
            int r = i >> 7, k = i & 127;
            ww[r][k] = wih[(size_t)(rb + r) * 512 + kc * 128 + k];
        }
        __syncthreads();
        for (int k = 0; k < 128; k++) {
            float xv = xs[k][b];
#pragma unroll
            for (int rr = 0; rr < 8; rr++)
                acc[rr] = fmaf(ww[rw * 8 + rr][k], xv, acc[rr]);
        }
    }
#pragma unroll
    for (int rr = 0; rr < 8; rr++) {
        int rg = rb + rw * 8 + rr;
        int g = rg >> 9, j = rg & 511;
        gix[((size_t)((size_t)t * 512 + j) * 3 + g) * 64 + b] = acc[rr];
    }
}

// fallback transpose x -> packed xT[t][k/4][b][4]
__global__ void k_xtk(const float* __restrict__ x, float* __restrict__ xT) {
    __shared__ float tile[64][65];
    int t = blockIdx.x >> 3, kc = blockIdx.x & 7;
    int k = threadIdx.x & 63, b0 = threadIdx.x >> 6;
    for (int i = 0; i < 16; i++) {
        int b = i * 4 + b0;
        tile[k][b] = x[(size_t)b * 262144 + (size_t)t * 512 + kc * 64 + k];
    }
    __syncthreads();
    int b2 = threadIdx.x & 63, k0 = threadIdx.x >> 6;
    for (int i = 0; i < 16; i++) {
        int k2 = kc * 64 + i * 4 + k0;
        xT[(size_t)t * 32768 + ((k2 >> 2) << 8) + (b2 << 2) + (k2 & 3)] = tile[i * 4 + k0][b2];
    }
}

// T1 = C2p * C1
__global__ void k_t1(const float* __restrict__ a1, const float* __restrict__ a2,
                     float* __restrict__ T1) {
    int l = blockIdx.x >> 10, c = blockIdx.x & 1023;
    int g = c >> 8, jj = c & 255;
    __shared__ float sA2[256];
    sA2[threadIdx.x] = a2[l * 65536 + jj * 256 + threadIdx.x];
    __syncthreads();
    const float* A1l = a1 + l * 262144;
    for (int colq = 0; colq < 4; colq++) {
        int col = colq * 256 + threadIdx.x;
        int half = col >> 9, cm = col & 511;
        float acc = 0.f;
#pragma unroll 4
        for (int q = 0; q < 64; q++) {
            int a0 = 2 * half;
            int j0 = g * 64 + q;
            acc = fmaf(sA2[4 * q + a0],     A1l[j0 * 512 + cm], acc);
            acc = fmaf(sA2[4 * q + a0 + 1], A1l[(j0 + 256) * 512 + cm], acc);
        }
        T1[((size_t)(l << 10) + c) * 1024 + col] = acc;
    }
}

// M = C3p * T1
__global__ void k_m(const float* __restrict__ a3, const float* __restrict__ T1,
                    float* __restrict__ M) {
    int l = blockIdx.x >> 10, c = blockIdx.x & 1023;
    int g = c >> 8, jj = c & 255;
    __shared__ float sA3[256];
    sA3[threadIdx.x] = a3[l * 65536 + jj * 256 + threadIdx.x];
    __syncthreads();
    const float* T1l = T1 + ((size_t)l << 20);
    for (int colq = 0; colq < 4; colq++) {
        int col = colq * 256 + threadIdx.x;
        float acc = 0.f;
#pragma unroll 4
        for (int m = 0; m < 256; m++) {
            int p = ((m & 3) << 8) + (g << 6) + (m >> 2);
            acc = fmaf(sA3[m], T1l[p * 1024 + col], acc);
        }
        M[((size_t)(l << 10) + c) * 1024 + col] = acc;
    }
}

// Persistent cooperative kernel. 256 blocks x 1024 threads, block owns 2 features.
// MERGED SUBSTAGES: each phase issues BOTH layers' exchange loads in ONE burst
// (they were all published before the phase's opening barrier), computes both
// into disjoint red2 slots, ONE __syncthreads, then disjoint reducer waves
// (w0-1 for l0, w2-3 for l1). Phase A additionally dedups hsG[l0] (l0's h-input
// == l1's x-input). Removes one full L3 round + 2 syncs per phase.
__global__ void __launch_bounds__(1024, 4)
persist(const float* __restrict__ x, const float* __restrict__ xT,
        const float* __restrict__ gix, int has_xt, int has_gix,
        const float* __restrict__ wih, const float* __restrict__ whh,
        const float* __restrict__ bih, const float* __restrict__ bhh,
        const float* __restrict__ Mc, const float* __restrict__ a4,
        float* __restrict__ ws, float* __restrict__ out) {
    __shared__ float wA[2][2][6][512];   // [l][f][d] d = gate*2+side (0=in,1=h)
    __shared__ float wM[2][4][1024];
    __shared__ float wD[2][2][1024];
    __shared__ float red2[14][16][64];
    __shared__ float bb[2][2][4];
    __shared__ float sH[2][2][64];       // [l][f][lane]

    const int tid = threadIdx.x, w = tid >> 6, lane = tid & 63, bid = blockIdx.x;

    for (int i = tid; i < 12288; i += 1024) {
        int l = i / 6144, r = i % 6144, f = r / 3072, r2 = r % 3072, d = r2 / 512, k = r2 & 511;
        int gate = d >> 1, side = d & 1;
        int j = 2 * bid + f;
        const float* src = side ? whh : wih;
        wA[l][f][d][k] = src[l * 786432 + (gate * 512 + j) * 512 + k];
    }
    for (int i = tid; i < 8192; i += 1024) {
        int l = i >> 12, r = (i >> 10) & 3, col = i & 1023;
        wM[l][r][col] = Mc[((size_t)(l << 10) + 4 * bid + r) * 1024 + col];
    }
    for (int i = tid; i < 4096; i += 1024) {
        int l = i >> 11, f = (i >> 10) & 1, k = i & 1023;
        wD[l][f][k] = a4[l * 524288 + (2 * bid + f) * 1024 + k];
    }
    if (tid < 16) {
        int l = tid / 8, f = (tid / 4) & 1, g = tid & 3;
        int j = 2 * bid + f;
        float v;
        if (g == 0)      v = bih[l * 1536 + j] + bhh[l * 1536 + j];
        else if (g == 1) v = bih[l * 1536 + 512 + j] + bhh[l * 1536 + 512 + j];
        else if (g == 2) v = bih[l * 1536 + 1024 + j];
        else             v = bhh[l * 1536 + 1024 + j];
        bb[l][f][g] = v;
    }
    __syncthreads();

    float* hsG = ws + OFF_HS;    // packed [l][128][64][4]
    float* hPg = ws + OFF_HP;    // packed
    float* sGg = ws + OFF_SG;    // packed
    float* uG  = ws + OFF_U;     // packed [l][256][64][4]
    unsigned* flags = (unsigned*)(ws + OFF_CTR);   // 256 lines
    unsigned bgen = 0;

    // Legacy stage A (used only when !has_gix; sequential substages)
    auto stageA_legacy = [&](int l, int t) {
        float hprev = 0.f;
        if (w < 2) {
            int j = 2 * bid + w;
            hprev = ld_sc1(&hsG[(l << 15) + ((j >> 2) << 8) + (lane << 2) + (j & 3)]);
        }
        const float* hb = hsG + (l << 15);
        float* hPl = hPg + (l << 15);
        int k0 = w * 32;
        const int koff = ((k0 >> 2) << 8) + (lane << 2);
        float acc[12];
#pragma unroll
        for (int u = 0; u < 12; u++) acc[u] = 0.f;
        f32x4 iv[8], hv[8];
        if (l == 1) {
            ld4b8x2(hsG + koff, hb + koff, iv, hv);
        } else if (has_xt) {
            ld4b8x2(xT + (size_t)t * 32768 + koff, hb + koff, iv, hv);
        } else {
#pragma unroll
            for (int m = 0; m < 8; m++)
#pragma unroll
                for (int q = 0; q < 4; q++)
                    iv[m][q] = x[(size_t)lane * 262144 + (size_t)t * 512 + k0 + 4 * m + q];
            ld4b8(hb + koff, hv);
        }
#pragma unroll
        for (int m = 0; m < 8; m++) {
#pragma unroll
            for (int q = 0; q < 4; q++) {
                int k = k0 + 4 * m + q;
                float ivq = iv[m][q], h = hv[m][q];
#pragma unroll
                for (int f = 0; f < 2; f++) {
                    acc[f * 6 + 0] = fmaf(wA[l][f][0][k], ivq, acc[f * 6 + 0]);
                    acc[f * 6 + 1] = fmaf(wA[l][f][1][k], h, acc[f * 6 + 1]);
                    acc[f * 6 + 2] = fmaf(wA[l][f][2][k], ivq, acc[f * 6 + 2]);
                    acc[f * 6 + 3] = fmaf(wA[l][f][3][k], h, acc[f * 6 + 3]);
                    acc[f * 6 + 4] = fmaf(wA[l][f][4][k], ivq, acc[f * 6 + 4]);
                    acc[f * 6 + 5] = fmaf(wA[l][f][5][k], h, acc[f * 6 + 5]);
                }
            }
        }
#pragma unroll
        for (int u = 0; u < 12; u++) red2[u][w][lane] = acc[u];
        __syncthreads();
        if (w < 2) {
            int f = w, j = 2 * bid + f;
            float g0 = 0, g1 = 0, g2 = 0, g3 = 0, g4 = 0, g5 = 0;
#pragma unroll
            for (int i = 0; i < 16; i++) {
                g0 += red2[f * 6 + 0][i][lane]; g1 += red2[f * 6 + 1][i][lane];
                g2 += red2[f * 6 + 2][i][lane]; g3 += red2[f * 6 + 3][i][lane];
                g4 += red2[f * 6 + 4][i][lane]; g5 += red2[f * 6 + 5][i][lane];
            }
            float r = sigm(g0 + g1 + bb[l][f][0]);
            float z = sigm(g2 + g3 + bb[l][f][1]);
            float n = tanhf(g4 + bb[l][f][2] + r * (g5 + bb[l][f][3]));
            float hp = (1.f - z) * n + z * hprev;
            sH[l][f][lane] = hp;
            st_sc1(&hPl[((j >> 2) << 8) + (lane << 2) + (j & 3)], hp);
        }
    };

    float accB0[4], accB1[4];

    for (int t = 0; t <= 512; t++) {
        const int t0 = t, t1 = t - 1;
        const bool do0 = (t0 < 512), do1 = (t1 >= 0);
        const int k0 = w * 32;
        const int koff = ((k0 >> 2) << 8) + (lane << 2);

        // ==== Phase A ====
        if (has_gix) {
            float hprev = 0.f, gx0 = 0.f, gx1 = 0.f, gx2 = 0.f;
            if (do0 && w < 2) {
                int j = 2 * bid + w;
                hprev = ld_sc1(&hsG[((j >> 2) << 8) + (lane << 2) + (j & 3)]);
                const float* gx = gix + ((size_t)((size_t)t0 * 512 + j) * 3) * 64;
                gx0 = gx[lane]; gx1 = gx[64 + lane]; gx2 = gx[128 + lane];
            }
            if (do1 && w >= 2 && w < 4) {
                int j = 2 * bid + (w - 2);
                hprev = ld_sc1(&hsG[(1 << 15) + ((j >> 2) << 8) + (lane << 2) + (j & 3)]);
            }
            f32x4 G0[8], G1[8];
            if (do1) ld4b8x2(hsG + koff, hsG + (1 << 15) + koff, G0, G1);
            else     ld4b8(hsG + koff, G0);

            if (do0) {
                float acc[6] = {0.f, 0.f, 0.f, 0.f, 0.f, 0.f};
#pragma unroll
                for (int m = 0; m < 8; m++) {
#pragma unroll
                    for (int q = 0; q < 4; q++) {
                        int k = k0 + 4 * m + q;
                        float h = G0[m][q];
#pragma unroll
                        for (int f = 0; f < 2; f++) {
                            acc[f * 3 + 0] = fmaf(wA[0][f][1][k], h, acc[f * 3 + 0]);
                            acc[f * 3 + 1] = fmaf(wA[0][f][3][k], h, acc[f * 3 + 1]);
                            acc[f * 3 + 2] = fmaf(wA[0][f][5][k], h, acc[f * 3 + 2]);
                        }
                    }
                }
#pragma unroll
                for (int u = 0; u < 6; u++) red2[u][w][lane] = acc[u];
            }
            if (do1) {
                float acc[12];
#pragma unroll
                for (int u = 0; u < 12; u++) acc[u] = 0.f;
#pragma unroll
                for (int m = 0; m < 8; m++) {
#pragma unroll
                    for (int q = 0; q < 4; q++) {
                        int k = k0 + 4 * m + q;
                        float ivq = G0[m][q], h = G1[m][q];
#pragma unroll
                        for (int f = 0; f < 2; f++) {
                            acc[f * 6 + 0] = fmaf(wA[1][f][0][k], ivq, acc[f * 6 + 0]);
                            acc[f * 6 + 1] = fmaf(wA[1][f][1][k], h, acc[f * 6 + 1]);
                            acc[f * 6 + 2] = fmaf(wA[1][f][2][k], ivq, acc[f * 6 + 2]);
                            acc[f * 6 + 3] = fmaf(wA[1][f][3][k], h, acc[f * 6 + 3]);
                            acc[f * 6 + 4] = fmaf(wA[1][f][4][k], ivq, acc[f * 6 + 4]);
                            acc[f * 6 + 5] = fmaf(wA[1][f][5][k], h, acc[f * 6 + 5]);
                        }
                    }
                }
#pragma unroll
                for (int f = 0; f < 2; f++) {
                    red2[6 + f * 4 + 0][w][lane] = acc[f * 6 + 0] + acc[f * 6 + 1];
                    red2[6 + f * 4 + 1][w][lane] = acc[f * 6 + 2] + acc[f * 6 + 3];
                    red2[6 + f * 4 + 2][w][lane] = acc[f * 6 + 4];
                    red2[6 + f * 4 + 3][w][lane] = acc[f * 6 + 5];
                }
            }
            __syncthreads();
            if (do0 && w < 2) {
                int f = w, j = 2 * bid + f;
                float s0 = 0, s1 = 0, s2 = 0;
#pragma unroll
                for (int i = 0; i < 16; i++) {
                    s0 += red2[f * 3 + 0][i][lane];
                    s1 += red2[f * 3 + 1][i][lane];
                    s2 += red2[f * 3 + 2][i][lane];
                }
                float r = sigm(gx0 + s0 + bb[0][f][0]);
                float z = sigm(gx1 + s1 + bb[0][f][1]);
                float n = tanhf(gx2 + bb[0][f][2] + r * (s2 + bb[0][f][3]));
                float hp = (1.f - z) * n + z * hprev;
                sH[0][f][lane] = hp;
                st_sc1(&hPg[((j >> 2) << 8) + (lane << 2) + (j & 3)], hp);
            }
            if (do1 && w >= 2 && w < 4) {
                int f = w - 2, j = 2 * bid + f;
                float rs = 0, zs = 0, g4 = 0, g5 = 0;
#pragma unroll
                for (int i = 0; i < 16; i++) {
                    rs += red2[6 + f * 4 + 0][i][lane];
                    zs += red2[6 + f * 4 + 1][i][lane];
                    g4 += red2[6 + f * 4 + 2][i][lane];
                    g5 += red2[6 + f * 4 + 3][i][lane];
                }
                float r = sigm(rs + bb[1][f][0]);
                float z = sigm(zs + bb[1][f][1]);
                float n = tanhf(g4 + bb[1][f][2] + r * (g5 + bb[1][f][3]));
                float hp = (1.f - z) * n + z * hprev;
                sH[1][f][lane] = hp;
                st_sc1(&hPg[(1 << 15) + ((j >> 2) << 8) + (lane << 2) + (j & 3)], hp);
            }
        } else {
            if (do0) stageA_legacy(0, t0);
            if (do1) { __syncthreads(); stageA_legacy(1, t1); }
        }
        gbar(flags, ++bgen);

        // ==== Phase B: ranks + h-half of C's matvec for BOTH layers ====
        {
            f32x4 H0[8], H1[8];
            if (do0 && do1) ld4b8x2(hPg + koff, hPg + (1 << 15) + koff, H0, H1);
            else if (do0)   ld4b8(hPg + koff, H0);
            else            ld4b8(hPg + (1 << 15) + koff, H1);
            int j0 = 2 * bid, j1 = j0 + 1;
            if (do0) {
                float v0 = sH[0][0][lane], v1 = sH[0][1][lane];
                int c0 = 0, c1 = 0;
                accB0[0] = accB0[1] = accB0[2] = accB0[3] = 0.f;
#pragma unroll
                for (int m = 0; m < 8; m++) {
#pragma unroll
                    for (int q = 0; q < 4; q++) {
                        int k = k0 + 4 * m + q;
                        float h = H0[m][q];
                        c0 += (h < v0 || (h == v0 && k < j0)) ? 1 : 0;
                        c1 += (h < v1 || (h == v1 && k < j1)) ? 1 : 0;
#pragma unroll
                        for (int r = 0; r < 4; r++)
                            accB0[r] = fmaf(wM[0][r][k], h, accB0[r]);
                    }
                }
                red2[0][w][lane] = (float)c0;
                red2[1][w][lane] = (float)c1;
            }
            if (do1) {
                float v0 = sH[1][0][lane], v1 = sH[1][1][lane];
                int c0 = 0, c1 = 0;
                accB1[0] = accB1[1] = accB1[2] = accB1[3] = 0.f;
#pragma unroll
                for (int m = 0; m < 8; m++) {
#pragma unroll
                    for (int q = 0; q < 4; q++) {
                        int k = k0 + 4 * m + q;
                        float h = H1[m][q];
                        c0 += (h < v0 || (h == v0 && k < j0)) ? 1 : 0;
                        c1 += (h < v1 || (h == v1 && k < j1)) ? 1 : 0;
#pragma unroll
                        for (int r = 0; r < 4; r++)
                            accB1[r] = fmaf(wM[1][r][k], h, accB1[r]);
                    }
                }
                red2[2][w][lane] = (float)c0;
                red2[3][w][lane] = (float)c1;
            }
            __syncthreads();
            if (w < 2 && do0) {
                int rk = 0;
#pragma unroll
                for (int i = 0; i < 16; i++) rk += (int)red2[w][i][lane];
                st_sc1(&sGg[((rk >> 2) << 8) + (lane << 2) + (rk & 3)], sH[0][w][lane]);
            }
            if (w >= 2 && w < 4 && do1) {
                int rk = 0;
#pragma unroll
                for (int i = 0; i < 16; i++) rk += (int)red2[w][i][lane];
                st_sc1(&sGg[(1 << 15) + ((rk >> 2) << 8) + (lane << 2) + (rk & 3)],
                       sH[1][w - 2][lane]);
            }
        }
        gbar(flags, ++bgen);

        // ==== Phase C: u = relu(M [h; s]) for BOTH layers (h-half from accB) ====
        {
            f32x4 S0[8], S1[8];
            if (do0 && do1) ld4b8x2(sGg + koff, sGg + (1 << 15) + koff, S0, S1);
            else if (do0)   ld4b8(sGg + koff, S0);
            else            ld4b8(sGg + (1 << 15) + koff, S1);
            if (do0) {
                float acc[4] = {accB0[0], accB0[1], accB0[2], accB0[3]};
#pragma unroll
                for (int m = 0; m < 8; m++) {
#pragma unroll
                    for (int q = 0; q < 4; q++) {
                        int sp = k0 + 4 * m + q;
                        float vv = S0[m][q];
#pragma unroll
                        for (int r = 0; r < 4; r++)
                            acc[r] = fmaf(wM[0][r][512 + sp], vv, acc[r]);
                    }
                }
#pragma unroll
                for (int r = 0; r < 4; r++) red2[r][w][lane] = acc[r];
            }
            if (do1) {
                float acc[4] = {accB1[0], accB1[1], accB1[2], accB1[3]};
#pragma unroll
                for (int m = 0; m < 8; m++) {
#pragma unroll
                    for (int q = 0; q < 4; q++) {
                        int sp = k0 + 4 * m + q;
                        float vv = S1[m][q];
#pragma unroll
                        for (int r = 0; r < 4; r++)
                            acc[r] = fmaf(wM[1][r][512 + sp], vv, acc[r]);
                    }
                }
#pragma unroll
                for (int r = 0; r < 4; r++) red2[4 + r][w][lane] = acc[r];
            }
            __syncthreads();
            if (w < 4) {
                bool act = (w < 2) ? do0 : do1;
                if (act) {
                    int l = w >> 1, s = w & 1;
                    float sa = 0.f, sb = 0.f;
#pragma unroll
                    for (int i = 0; i < 16; i++) {
                        sa += red2[w * 2][i][lane];
                        sb += red2[w * 2 + 1][i][lane];
                    }
                    st2(&uG[(l << 16) + (bid << 8) + (lane << 2) + 2 * s],
                        fmaxf(sa, 0.f), fmaxf(sb, 0.f));
                }
            }
        }
        gbar(flags, ++bgen);

        // ==== Phase D: scores + state update for BOTH layers ====
        {
            const int kd0 = w * 64;
            const int kdoff = ((kd0 >> 2) << 8) + (lane << 2);
            f32x4 U[8], V[8];
            if (do0) {
                ld4b8x2(uG + kdoff, uG + kdoff + 2048, U, V);
                float a0 = 0.f, a1 = 0.f;
#pragma unroll
                for (int m = 0; m < 8; m++)
#pragma unroll
                    for (int q = 0; q < 4; q++) {
                        int k = kd0 + 4 * m + q;
                        a0 = fmaf(wD[0][0][k], U[m][q], a0);
                        a1 = fmaf(wD[0][1][k], U[m][q], a1);
                    }
#pragma unroll
                for (int m = 0; m < 8; m++)
#pragma unroll
                    for (int q = 0; q < 4; q++) {
                        int k = kd0 + 32 + 4 * m + q;
                        a0 = fmaf(wD[0][0][k], V[m][q], a0);
                        a1 = fmaf(wD[0][1][k], V[m][q], a1);
                    }
                red2[0][w][lane] = a0;
                red2[1][w][lane] = a1;
            }
            if (do1) {
                ld4b8x2(uG + (1 << 16) + kdoff, uG + (1 << 16) + kdoff + 2048, U, V);
                float a0 = 0.f, a1 = 0.f;
#pragma unroll
                for (int m = 0; m < 8; m++)
#pragma unroll
                    for (int q = 0; q < 4; q++) {
                        int k = kd0 + 4 * m + q;
                        a0 = fmaf(wD[1][0][k], U[m][q], a0);
                        a1 = fmaf(wD[1][1][k], U[m][q], a1);
                    }
#pragma unroll
                for (int m = 0; m < 8; m++)
#pragma unroll
                    for (int q = 0; q < 4; q++) {
                        int k = kd0 + 32 + 4 * m + q;
                        a0 = fmaf(wD[1][0][k], V[m][q], a0);
                        a1 = fmaf(wD[1][1][k], V[m][q], a1);
                    }
                red2[2][w][lane] = a0;
                red2[3][w][lane] = a1;
            }
            __syncthreads();
            if (w < 4) {
                bool act = (w < 2) ? do0 : do1;
                if (act) {
                    int l = w >> 1, f = w & 1, j = 2 * bid + f;
                    float s = 0.f;
#pragma unroll
                    for (int i = 0; i < 16; i++) s += red2[w][i][lane];
                    float hnew = sH[l][f][lane] * sigm(s);
                    st_sc1(&hsG[(l << 15) + ((j >> 2) << 8) + (lane << 2) + (j & 3)], hnew);
                    if (l == 1)
                        out[(size_t)lane * 262144 + (size_t)t1 * 512 + j] = hnew;
                }
            }
        }
        gbar(flags, ++bgen);
    }
}

extern "C" void kernel_launch(void* const* d_in, const int* in_sizes, int n_in,
                              void* d_out, int out_size, void* d_ws, size_t ws_size,
                              hipStream_t stream) {
    const float* x   = (const float*)d_in[0];
    const float* h0  = (const float*)d_in[1];
    const float* wih = (const float*)d_in[2];
    const float* whh = (const float*)d_in[3];
    const float* bih = (const float*)d_in[4];
    const float* bhh = (const float*)d_in[5];
    const float* a1  = (const float*)d_in[6];
    const float* a2  = (const float*)d_in[7];
    const float* a3  = (const float*)d_in[8];
    const float* a4  = (const float*)d_in[9];
    float* ws  = (float*)d_ws;
    float* out = (float*)d_out;

    int has_gix = (ws_size >= (size_t)WS_GIX * 4) ? 1 : 0;
    int has_xt  = (!has_gix && ws_size >= (size_t)WS_XT * 4) ? 1 : 0;
    float* T1p = ws + OFF_T1;
    float* Mp  = ws + OFF_M;
    const float* gixp = ws + OFF_GIX;
    const float* xTp  = ws + OFF_XT;

    hipLaunchKernelGGL(k_init, dim3(256), dim3(256), 0, stream, h0, ws);
    if (has_gix)
        hipLaunchKernelGGL(k_gix, dim3(512, 48), dim3(256), 0, stream, x, wih, ws + OFF_GIX);
    else if (has_xt)
        hipLaunchKernelGGL(k_xtk, dim3(4096), dim3(256), 0, stream, x, ws + OFF_XT);
    hipLaunchKernelGGL(k_t1, dim3(2048), dim3(256), 0, stream, a1, a2, T1p);
    hipLaunchKernelGGL(k_m, dim3(2048), dim3(256), 0, stream, a3, T1p, Mp);

    void* args[] = {(void*)&x, (void*)&xTp, (void*)&gixp, (void*)&has_xt, (void*)&has_gix,
                    (void*)&wih, (void*)&whh, (void*)&bih, (void*)&bhh,
                    (void*)&Mp, (void*)&a4, (void*)&ws, (void*)&out};
    hipLaunchCooperativeKernel((void*)persist, dim3(256), dim3(1024), args, 0, stream);
}

// Round 12
// 43400.104 us; speedup vs baseline: 1.5522x; 1.5522x over previous
//
#include <hip/hip_runtime.h>

#define SCOPE_AGENT __HIP_MEMORY_SCOPE_AGENT

// ws layout (float offsets)
// PACKED-4 exchange layout for hsG/hPg/sGg/uG: element (k,lane) at
// ((k>>2)*256 + lane*4 + (k&3)). Consumers load 16B groups with
// global_load_dwordx4 sc1 (agent scope, served from L3).
#define OFF_HS    0          // [2] packed [128][64][4] hidden states
#define OFF_HP    65536      // [2] packed h'
#define OFF_SG    131072     // [2] packed sorted
#define OFF_U     196608     // [2] packed [256][64][4] u
#define OFF_CTR   327680     // barrier: flag[256] lines (uint stride 32)
#define OFF_T1    393216     // [2][1024][1024] compose scratch
#define OFF_M     2490368    // [2][1024][1024] composed M
#define OFF_GIX   4587520    // [512][512][3][64] precomputed W_ih. x_t (layer 0)
#define OFF_XT    4587520    // fallback: packed [512][128][64][4] transposed x
#define WS_GIX    54919168   // floats incl gix (~220 MB)
#define WS_XT     21364736   // floats incl xT (~85 MB)

typedef float f32x4 __attribute__((ext_vector_type(4)));

__device__ __forceinline__ float sigm(float x) { return 1.f / (1.f + expf(-x)); }

__device__ __forceinline__ float ld_sc1(const float* p) {
    return __hip_atomic_load(p, __ATOMIC_RELAXED, SCOPE_AGENT);
}
__device__ __forceinline__ void st_sc1(float* p, float v) {
    __hip_atomic_store(p, v, __ATOMIC_RELAXED, SCOPE_AGENT);
}
__device__ __forceinline__ void st2(float* p, float a, float b) {
    unsigned long long v = ((unsigned long long)__float_as_uint(b) << 32) |
                           (unsigned long long)__float_as_uint(a);
    __hip_atomic_store((unsigned long long*)p, v, __ATOMIC_RELAXED, SCOPE_AGENT);
}

// 8 x 16B agent-scope loads, one latency round.
__device__ __forceinline__ void ld4b8(const float* base, f32x4* v) {
    const float* b2 = base + 1024;
    asm volatile(
        "global_load_dwordx4 %0, %8, off sc1\n\t"
        "global_load_dwordx4 %1, %8, off offset:1024 sc1\n\t"
        "global_load_dwordx4 %2, %8, off offset:2048 sc1\n\t"
        "global_load_dwordx4 %3, %8, off offset:3072 sc1\n\t"
        "global_load_dwordx4 %4, %9, off sc1\n\t"
        "global_load_dwordx4 %5, %9, off offset:1024 sc1\n\t"
        "global_load_dwordx4 %6, %9, off offset:2048 sc1\n\t"
        "global_load_dwordx4 %7, %9, off offset:3072 sc1\n\t"
        "s_waitcnt vmcnt(0)"
        : "=&v"(v[0]), "=&v"(v[1]), "=&v"(v[2]), "=&v"(v[3]),
          "=&v"(v[4]), "=&v"(v[5]), "=&v"(v[6]), "=&v"(v[7])
        : "v"(base), "v"(b2)
        : "memory");
}

// 16 x 16B loads from two regions (8 each), SINGLE waitcnt -> one latency round.
__device__ __forceinline__ void ld4b8x2(const float* baseA, const float* baseB,
                                        f32x4* va, f32x4* vb) {
    const float* a2 = baseA + 1024;
    const float* b2 = baseB + 1024;
    asm volatile(
        "global_load_dwordx4 %0, %16, off sc1\n\t"
        "global_load_dwordx4 %1, %16, off offset:1024 sc1\n\t"
        "global_load_dwordx4 %2, %16, off offset:2048 sc1\n\t"
        "global_load_dwordx4 %3, %16, off offset:3072 sc1\n\t"
        "global_load_dwordx4 %4, %17, off sc1\n\t"
        "global_load_dwordx4 %5, %17, off offset:1024 sc1\n\t"
        "global_load_dwordx4 %6, %17, off offset:2048 sc1\n\t"
        "global_load_dwordx4 %7, %17, off offset:3072 sc1\n\t"
        "global_load_dwordx4 %8, %18, off sc1\n\t"
        "global_load_dwordx4 %9, %18, off offset:1024 sc1\n\t"
        "global_load_dwordx4 %10, %18, off offset:2048 sc1\n\t"
        "global_load_dwordx4 %11, %18, off offset:3072 sc1\n\t"
        "global_load_dwordx4 %12, %19, off sc1\n\t"
        "global_load_dwordx4 %13, %19, off offset:1024 sc1\n\t"
        "global_load_dwordx4 %14, %19, off offset:2048 sc1\n\t"
        "global_load_dwordx4 %15, %19, off offset:3072 sc1\n\t"
        "s_waitcnt vmcnt(0)"
        : "=&v"(va[0]), "=&v"(va[1]), "=&v"(va[2]), "=&v"(va[3]),
          "=&v"(va[4]), "=&v"(va[5]), "=&v"(va[6]), "=&v"(va[7]),
          "=&v"(vb[0]), "=&v"(vb[1]), "=&v"(vb[2]), "=&v"(vb[3]),
          "=&v"(vb[4]), "=&v"(vb[5]), "=&v"(vb[6]), "=&v"(vb[7])
        : "v"(baseA), "v"(a2), "v"(baseB), "v"(b2)
        : "memory");
}

// FLAT single-hop barrier: every block stores flag[bid]=g; threads 0..255 of
// EVERY block each poll one flag. No scanner, no release store. Generation-
// tagged, no resets.
__device__ __forceinline__ void gbar(unsigned* flags, unsigned g) {
    __syncthreads();
    const int tid = threadIdx.x;
    if (tid == 0)
        __hip_atomic_store(&flags[blockIdx.x << 5], g, __ATOMIC_RELAXED, SCOPE_AGENT);
    if (tid < 256) {
        while (__hip_atomic_load(&flags[tid << 5], __ATOMIC_RELAXED, SCOPE_AGENT) < g)
            __builtin_amdgcn_s_sleep(1);
    }
    __syncthreads();
}

__global__ void k_init(const float* __restrict__ h0, float* __restrict__ ws) {
    int idx = blockIdx.x * blockDim.x + threadIdx.x;   // 65536
    int l = idx >> 15, k = (idx & 32767) >> 6, lane = idx & 63;
    ws[OFF_HS + (l << 15) + ((k >> 2) << 8) + (lane << 2) + (k & 3)] = h0[(l << 9) + k];
    if (idx < 8704) ((unsigned*)(ws + OFF_CTR))[idx] = 0u;
}

// gix[t][j][g][b] = sum_k wih0[g*512+j][k] * x[b][t*512+k]
__global__ void k_gix(const float* __restrict__ x, const float* __restrict__ wih,
                      float* __restrict__ gix) {
    __shared__ float xs[128][65];
    __shared__ float ww[32][129];
    int t = blockIdx.x, rb = blockIdx.y * 32;
    int tid = threadIdx.x;
    int rw = tid >> 6, b = tid & 63;
    float acc[8] = {0.f, 0.f, 0.f, 0.f, 0.f, 0.f, 0.f, 0.f};
    for (int kc = 0; kc < 4; kc++) {
        __syncthreads();
        for (int i = tid; i < 8192; i += 256) {
            int k = i & 127, b2 = i >> 7;
            xs[k][b2] = x[(size_t)b2 * 262144 + (size_t)t * 512 + kc * 128 + k];
        }
        for (int i = tid; i < 4096; i += 256) {
            int r = i >> 7, k = i & 127;
            ww[r][k] = wih[(size_t)(rb + r) * 512 + kc * 128 + k];
        }
        __syncthreads();
        for (int k = 0; k < 128; k++) {
            float xv = xs[k][b];
#pragma unroll
            for (int rr = 0; rr < 8; rr++)
                acc[rr] = fmaf(ww[rw * 8 + rr][k], xv, acc[rr]);
        }
    }
#pragma unroll
    for (int rr = 0; rr < 8; rr++) {
        int rg = rb + rw * 8 + rr;
        int g = rg >> 9, j = rg & 511;
        gix[((size_t)((size_t)t * 512 + j) * 3 + g) * 64 + b] = acc[rr];
    }
}

// fallback transpose x -> packed xT[t][k/4][b][4]
__global__ void k_xtk(const float* __restrict__ x, float* __restrict__ xT) {
    __shared__ float tile[64][65];
    int t = blockIdx.x >> 3, kc = blockIdx.x & 7;
    int k = threadIdx.x & 63, b0 = threadIdx.x >> 6;
    for (int i = 0; i < 16; i++) {
        int b = i * 4 + b0;
        tile[k][b] = x[(size_t)b * 262144 + (size_t)t * 512 + kc * 64 + k];
    }
    __syncthreads();
    int b2 = threadIdx.x & 63, k0 = threadIdx.x >> 6;
    for (int i = 0; i < 16; i++) {
        int k2 = kc * 64 + i * 4 + k0;
        xT[(size_t)t * 32768 + ((k2 >> 2) << 8) + (b2 << 2) + (k2 & 3)] = tile[i * 4 + k0][b2];
    }
}

// T1 = C2p * C1
__global__ void k_t1(const float* __restrict__ a1, const float* __restrict__ a2,
                     float* __restrict__ T1) {
    int l = blockIdx.x >> 10, c = blockIdx.x & 1023;
    int g = c >> 8, jj = c & 255;
    __shared__ float sA2[256];
    sA2[threadIdx.x] = a2[l * 65536 + jj * 256 + threadIdx.x];
    __syncthreads();
    const float* A1l = a1 + l * 262144;
    for (int colq = 0; colq < 4; colq++) {
        int col = colq * 256 + threadIdx.x;
        int half = col >> 9, cm = col & 511;
        float acc = 0.f;
#pragma unroll 4
        for (int q = 0; q < 64; q++) {
            int a0 = 2 * half;
            int j0 = g * 64 + q;
            acc = fmaf(sA2[4 * q + a0],     A1l[j0 * 512 + cm], acc);
            acc = fmaf(sA2[4 * q + a0 + 1], A1l[(j0 + 256) * 512 + cm], acc);
        }
        T1[((size_t)(l << 10) + c) * 1024 + col] = acc;
    }
}

// M = C3p * T1
__global__ void k_m(const float* __restrict__ a3, const float* __restrict__ T1,
                    float* __restrict__ M) {
    int l = blockIdx.x >> 10, c = blockIdx.x & 1023;
    int g = c >> 8, jj = c & 255;
    __shared__ float sA3[256];
    sA3[threadIdx.x] = a3[l * 65536 + jj * 256 + threadIdx.x];
    __syncthreads();
    const float* T1l = T1 + ((size_t)l << 20);
    for (int colq = 0; colq < 4; colq++) {
        int col = colq * 256 + threadIdx.x;
        float acc = 0.f;
#pragma unroll 4
        for (int m = 0; m < 256; m++) {
            int p = ((m & 3) << 8) + (g << 6) + (m >> 2);
            acc = fmaf(sA3[m], T1l[p * 1024 + col], acc);
        }
        M[((size_t)(l << 10) + c) * 1024 + col] = acc;
    }
}

// Persistent cooperative kernel. 256 blocks x 1024 threads, block owns 2 features.
// Flat one-hop barrier; one load-latency round per stage (merged 16-load batches).
// This is the R10 configuration (measured best: 41.0 ms persist) — R11's
// merged-substage variant regressed via VGPR spill traffic and is reverted.
__global__ void __launch_bounds__(1024, 4)
persist(const float* __restrict__ x, const float* __restrict__ xT,
        const float* __restrict__ gix, int has_xt, int has_gix,
        const float* __restrict__ wih, const float* __restrict__ whh,
        const float* __restrict__ bih, const float* __restrict__ bhh,
        const float* __restrict__ Mc, const float* __restrict__ a4,
        float* __restrict__ ws, float* __restrict__ out) {
    __shared__ float wA[2][2][6][512];   // [l][f][d] d = gate*2+side (0=in,1=h)
    __shared__ float wM[2][4][1024];
    __shared__ float wD[2][2][1024];
    __shared__ float red2[12][16][64];
    __shared__ float bb[2][2][4];
    __shared__ float sH[2][2][64];       // [l][f][lane]

    const int tid = threadIdx.x, w = tid >> 6, lane = tid & 63, bid = blockIdx.x;

    for (int i = tid; i < 12288; i += 1024) {
        int l = i / 6144, r = i % 6144, f = r / 3072, r2 = r % 3072, d = r2 / 512, k = r2 & 511;
        int gate = d >> 1, side = d & 1;
        int j = 2 * bid + f;
        const float* src = side ? whh : wih;
        wA[l][f][d][k] = src[l * 786432 + (gate * 512 + j) * 512 + k];
    }
    for (int i = tid; i < 8192; i += 1024) {
        int l = i >> 12, r = (i >> 10) & 3, col = i & 1023;
        wM[l][r][col] = Mc[((size_t)(l << 10) + 4 * bid + r) * 1024 + col];
    }
    for (int i = tid; i < 4096; i += 1024) {
        int l = i >> 11, f = (i >> 10) & 1, k = i & 1023;
        wD[l][f][k] = a4[l * 524288 + (2 * bid + f) * 1024 + k];
    }
    if (tid < 16) {
        int l = tid / 8, f = (tid / 4) & 1, g = tid & 3;
        int j = 2 * bid + f;
        float v;
        if (g == 0)      v = bih[l * 1536 + j] + bhh[l * 1536 + j];
        else if (g == 1) v = bih[l * 1536 + 512 + j] + bhh[l * 1536 + 512 + j];
        else if (g == 2) v = bih[l * 1536 + 1024 + j];
        else             v = bhh[l * 1536 + 1024 + j];
        bb[l][f][g] = v;
    }
    __syncthreads();

    float* hsG = ws + OFF_HS;    // packed [l][128][64][4]
    float* hPg = ws + OFF_HP;    // packed
    float* sGg = ws + OFF_SG;    // packed
    float* uG  = ws + OFF_U;     // packed [l][256][64][4]
    unsigned* flags = (unsigned*)(ws + OFF_CTR);   // 256 lines
    unsigned bgen = 0;

    // ---- Stage A: GRU gates + h' ----
    auto stageA = [&](int l, int t) {
        float hprev = 0.f;
        if (w < 2) {
            int j = 2 * bid + w;
            hprev = ld_sc1(&hsG[(l << 15) + ((j >> 2) << 8) + (lane << 2) + (j & 3)]);
        }
        const float* hb = hsG + (l << 15);
        float* hPl = hPg + (l << 15);
        int k0 = w * 32;
        const int koff = ((k0 >> 2) << 8) + (lane << 2);
        if (l == 0 && has_gix) {
            float acc[6] = {0.f, 0.f, 0.f, 0.f, 0.f, 0.f};
            f32x4 hv[8];
            ld4b8(hb + koff, hv);
#pragma unroll
            for (int m = 0; m < 8; m++) {
#pragma unroll
                for (int q = 0; q < 4; q++) {
                    int k = k0 + 4 * m + q;
                    float h = hv[m][q];
#pragma unroll
                    for (int f = 0; f < 2; f++) {
                        acc[f * 3 + 0] = fmaf(wA[0][f][1][k], h, acc[f * 3 + 0]);
                        acc[f * 3 + 1] = fmaf(wA[0][f][3][k], h, acc[f * 3 + 1]);
                        acc[f * 3 + 2] = fmaf(wA[0][f][5][k], h, acc[f * 3 + 2]);
                    }
                }
            }
#pragma unroll
            for (int u = 0; u < 6; u++) red2[u][w][lane] = acc[u];
            __syncthreads();
            if (w < 2) {
                int f = w, j = 2 * bid + f;
                float s0 = 0, s1 = 0, s2 = 0;
#pragma unroll
                for (int i = 0; i < 16; i++) {
                    s0 += red2[f * 3 + 0][i][lane];
                    s1 += red2[f * 3 + 1][i][lane];
                    s2 += red2[f * 3 + 2][i][lane];
                }
                const float* gx = gix + ((size_t)((size_t)t * 512 + j) * 3) * 64;
                float r = sigm(gx[lane] + s0 + bb[0][f][0]);
                float z = sigm(gx[64 + lane] + s1 + bb[0][f][1]);
                float n = tanhf(gx[128 + lane] + bb[0][f][2] + r * (s2 + bb[0][f][3]));
                float hp = (1.f - z) * n + z * hprev;
                sH[0][f][lane] = hp;
                st_sc1(&hPl[((j >> 2) << 8) + (lane << 2) + (j & 3)], hp);
            }
        } else {
            float acc[12];
#pragma unroll
            for (int u = 0; u < 12; u++) acc[u] = 0.f;
            f32x4 iv[8], hv[8];
            if (l == 1) {
                ld4b8x2(hsG + koff, hb + koff, iv, hv);
            } else if (has_xt) {
                ld4b8x2(xT + (size_t)t * 32768 + koff, hb + koff, iv, hv);
            } else {
#pragma unroll
                for (int m = 0; m < 8; m++)
#pragma unroll
                    for (int q = 0; q < 4; q++)
                        iv[m][q] = x[(size_t)lane * 262144 + (size_t)t * 512 + k0 + 4 * m + q];
                ld4b8(hb + koff, hv);
            }
#pragma unroll
            for (int m = 0; m < 8; m++) {
#pragma unroll
                for (int q = 0; q < 4; q++) {
                    int k = k0 + 4 * m + q;
                    float ivq = iv[m][q];
#pragma unroll
                    for (int f = 0; f < 2; f++) {
                        acc[f * 6 + 0] = fmaf(wA[l][f][0][k], ivq, acc[f * 6 + 0]);
                        acc[f * 6 + 2] = fmaf(wA[l][f][2][k], ivq, acc[f * 6 + 2]);
                        acc[f * 6 + 4] = fmaf(wA[l][f][4][k], ivq, acc[f * 6 + 4]);
                    }
                }
            }
#pragma unroll
            for (int m = 0; m < 8; m++) {
#pragma unroll
                for (int q = 0; q < 4; q++) {
                    int k = k0 + 4 * m + q;
                    float h = hv[m][q];
#pragma unroll
                    for (int f = 0; f < 2; f++) {
                        acc[f * 6 + 1] = fmaf(wA[l][f][1][k], h, acc[f * 6 + 1]);
                        acc[f * 6 + 3] = fmaf(wA[l][f][3][k], h, acc[f * 6 + 3]);
                        acc[f * 6 + 5] = fmaf(wA[l][f][5][k], h, acc[f * 6 + 5]);
                    }
                }
            }
#pragma unroll
            for (int u = 0; u < 12; u++) red2[u][w][lane] = acc[u];
            __syncthreads();
            if (w < 2) {
                int f = w, j = 2 * bid + f;
                float g0 = 0, g1 = 0, g2 = 0, g3 = 0, g4 = 0, g5 = 0;
#pragma unroll
                for (int i = 0; i < 16; i++) {
                    g0 += red2[f * 6 + 0][i][lane]; g1 += red2[f * 6 + 1][i][lane];
                    g2 += red2[f * 6 + 2][i][lane]; g3 += red2[f * 6 + 3][i][lane];
                    g4 += red2[f * 6 + 4][i][lane]; g5 += red2[f * 6 + 5][i][lane];
                }
                float r = sigm(g0 + g1 + bb[l][f][0]);
                float z = sigm(g2 + g3 + bb[l][f][1]);
                float n = tanhf(g4 + bb[l][f][2] + r * (g5 + bb[l][f][3]));
                float hp = (1.f - z) * n + z * hprev;
                sH[l][f][lane] = hp;
                st_sc1(&hPl[((j >> 2) << 8) + (lane << 2) + (j & 3)], hp);
            }
        }
    };

    // ---- Stage B: ranks + h-half partial of C's matvec (accB[4] in regs) ----
    auto stageB = [&](int l, float* accB) {
        int j0 = 2 * bid, j1 = j0 + 1;
        float v0 = sH[l][0][lane], v1 = sH[l][1][lane];
        const float* hPl = hPg + (l << 15);
        float* sGl = sGg + (l << 15);
        int k0 = w * 32, cnt0 = 0, cnt1 = 0;
        accB[0] = accB[1] = accB[2] = accB[3] = 0.f;
        f32x4 hv[8];
        ld4b8(hPl + ((k0 >> 2) << 8) + (lane << 2), hv);
#pragma unroll
        for (int m = 0; m < 8; m++) {
#pragma unroll
            for (int q = 0; q < 4; q++) {
                int k = k0 + 4 * m + q;
                float h = hv[m][q];
                cnt0 += (h < v0 || (h == v0 && k < j0)) ? 1 : 0;
                cnt1 += (h < v1 || (h == v1 && k < j1)) ? 1 : 0;
#pragma unroll
                for (int r = 0; r < 4; r++)
                    accB[r] = fmaf(wM[l][r][k], h, accB[r]);
            }
        }
        red2[0][w][lane] = (float)cnt0;
        red2[1][w][lane] = (float)cnt1;
        __syncthreads();
        if (w < 2) {
            int rk = 0;
#pragma unroll
            for (int i = 0; i < 16; i++) rk += (int)red2[w][i][lane];
            st_sc1(&sGl[((rk >> 2) << 8) + (lane << 2) + (rk & 3)], sH[l][w][lane]);
        }
    };

    // ---- Stage C: u = relu(M [h; s]); s-half only (h-half from accB) ----
    auto stageC = [&](int l, const float* accB) {
        float acc[4] = {accB[0], accB[1], accB[2], accB[3]};
        int s0 = w * 32;
        const float* sGl = sGg + (l << 15);
        f32x4 sv[8];
        ld4b8(sGl + ((s0 >> 2) << 8) + (lane << 2), sv);
#pragma unroll
        for (int m = 0; m < 8; m++) {
#pragma unroll
            for (int q = 0; q < 4; q++) {
                int sp = s0 + 4 * m + q;
                float vv = sv[m][q];
#pragma unroll
                for (int r = 0; r < 4; r++)
                    acc[r] = fmaf(wM[l][r][512 + sp], vv, acc[r]);
            }
        }
#pragma unroll
        for (int r = 0; r < 4; r++) red2[r][w][lane] = acc[r];
        __syncthreads();
        if (w < 2) {
            float sa = 0.f, sb = 0.f;
#pragma unroll
            for (int i = 0; i < 16; i++) {
                sa += red2[2 * w + 0][i][lane];
                sb += red2[2 * w + 1][i][lane];
            }
            st2(&uG[(l << 16) + (bid << 8) + (lane << 2) + (w << 1)],
                fmaxf(sa, 0.f), fmaxf(sb, 0.f));
        }
    };

    // ---- Stage D: scores + state update (single 16-load round) ----
    auto stageD = [&](int l, int t) {
        float a0 = 0.f, a1v = 0.f;
        int k0 = w * 64;
        const float* uL = uG + (l << 16);
        f32x4 uv[8], uw[8];
        ld4b8x2(uL + ((k0 >> 2) << 8) + (lane << 2),
                uL + (((k0 >> 2) + 8) << 8) + (lane << 2), uv, uw);
#pragma unroll
        for (int m = 0; m < 8; m++)
#pragma unroll
            for (int q = 0; q < 4; q++) {
                int k = k0 + 4 * m + q;
                a0 = fmaf(wD[l][0][k], uv[m][q], a0);
                a1v = fmaf(wD[l][1][k], uv[m][q], a1v);
            }
#pragma unroll
        for (int m = 0; m < 8; m++)
#pragma unroll
            for (int q = 0; q < 4; q++) {
                int k = k0 + 32 + 4 * m + q;
                a0 = fmaf(wD[l][0][k], uw[m][q], a0);
                a1v = fmaf(wD[l][1][k], uw[m][q], a1v);
            }
        red2[0][w][lane] = a0;
        red2[1][w][lane] = a1v;
        __syncthreads();
        if (w < 2) {
            float s = 0.f;
#pragma unroll
            for (int i = 0; i < 16; i++) s += red2[w][i][lane];
            float hnew = sH[l][w][lane] * sigm(s);
            int j = 2 * bid + w;
            st_sc1(&hsG[(l << 15) + ((j >> 2) << 8) + (lane << 2) + (j & 3)], hnew);
            if (l == 1)
                out[(size_t)lane * 262144 + (size_t)t * 512 + j] = hnew;
        }
    };

    float accB0[4], accB1[4];

    // Pipelined main loop: iteration t runs (layer0, t) and (layer1, t-1).
    for (int t = 0; t <= 512; t++) {
        const int t0 = t, t1 = t - 1;
        const bool do0 = (t0 < 512), do1 = (t1 >= 0);

        if (do0) stageA(0, t0);
        if (do1) { __syncthreads(); stageA(1, t1); }
        gbar(flags, ++bgen);

        if (do0) stageB(0, accB0);
        if (do1) { __syncthreads(); stageB(1, accB1); }
        gbar(flags, ++bgen);

        if (do0) stageC(0, accB0);
        if (do1) { __syncthreads(); stageC(1, accB1); }
        gbar(flags, ++bgen);

        if (do0) stageD(0, t0);
        if (do1) { __syncthreads(); stageD(1, t1); }
        gbar(flags, ++bgen);
    }
}

extern "C" void kernel_launch(void* const* d_in, const int* in_sizes, int n_in,
                              void* d_out, int out_size, void* d_ws, size_t ws_size,
                              hipStream_t stream) {
    const float* x   = (const float*)d_in[0];
    const float* h0  = (const float*)d_in[1];
    const float* wih = (const float*)d_in[2];
    const float* whh = (const float*)d_in[3];
    const float* bih = (const float*)d_in[4];
    const float* bhh = (const float*)d_in[5];
    const float* a1  = (const float*)d_in[6];
    const float* a2  = (const float*)d_in[7];
    const float* a3  = (const float*)d_in[8];
    const float* a4  = (const float*)d_in[9];
    float* ws  = (float*)d_ws;
    float* out = (float*)d_out;

    int has_gix = (ws_size >= (size_t)WS_GIX * 4) ? 1 : 0;
    int has_xt  = (!has_gix && ws_size >= (size_t)WS_XT * 4) ? 1 : 0;
    float* T1p = ws + OFF_T1;
    float* Mp  = ws + OFF_M;
    const float* gixp = ws + OFF_GIX;
    const float* xTp  = ws + OFF_XT;

    hipLaunchKernelGGL(k_init, dim3(256), dim3(256), 0, stream, h0, ws);
    if (has_gix)
        hipLaunchKernelGGL(k_gix, dim3(512, 48), dim3(256), 0, stream, x, wih, ws + OFF_GIX);
    else if (has_xt)
        hipLaunchKernelGGL(k_xtk, dim3(4096), dim3(256), 0, stream, x, ws + OFF_XT);
    hipLaunchKernelGGL(k_t1, dim3(2048), dim3(256), 0, stream, a1, a2, T1p);
    hipLaunchKernelGGL(k_m, dim3(2048), dim3(256), 0, stream, a3, T1p, Mp);

    void* args[] = {(void*)&x, (void*)&xTp, (void*)&gixp, (void*)&has_xt, (void*)&has_gix,
                    (void*)&wih, (void*)&whh, (void*)&bih, (void*)&bhh,
                    (void*)&Mp, (void*)&a4, (void*)&ws, (void*)&out};
    hipLaunchCooperativeKernel((void*)persist, dim3(256), dim3(1024), args, 0, stream);
}